// Round 18
// baseline (230.283 us; speedup 1.0000x reference)
//
#include <hip/hip_runtime.h>

// ---------------- problem constants ----------------
// B=8, T=32, S=256, DV=1024, NH=16, dh=64, DA=512, L2=2048
// video_x: [8, 8192, 1024] f32   audio_x: [8, 2048, 512] f32
// out: [8, 32, 2048] f32
//
// MEASURED (R3-R17): 512-thr/(512,2) = no spill; R15 structure + early
// prefetch = 173us. This round: (1) XOR-swizzle k1's bf16 LDS tiles
// (row-stride 528 dwords = 16 mod 32 -> 8-way conflict on MFMA operand
// reads; swz col^=(row&7)<<3 makes rows 0-7 hit 8 distinct banks, rows
// r/r+8 a free 2-way); (2) ctxx stored bf16 (-16MB HBM round trip);
// (3) qflat+qwt merged into k_qprep (block h self-contained).
//
// Pipeline (f32 except bf16 MFMA operands + bf16 ctxx):
//  qprep: qf(h-slice) -> qwt_hd[h][d], qbs[h]
//  k1: S=x_bf@qw_bf^T (MFMA); p=exp(S+qb); ctxx_bf16[h][d]=sum_s p*x /l
//  G1: ctx = ctxx_bf16(head-block) @ wv^T         (K-split 2 -> ctxp)
//  G2: pool = (ctxp0+ctxp1+bv) @ wo^T             (K-split 2 -> poolp)
//  LN: lno = LN(poolp0+poolp1+bo)
//  G3: vt = lno @ pw^T                            (K-split 2 -> vtp)
//  sim: (norm(vtp0+vtp1+pb) . norm(audio)) * exp(ls) + lb

// ---- ws layout (float offsets; CTXX region holds bf16, oversized) ----
#define FB_QWT    0u                       // [16][1024]  (h-major)
#define FB_QB     16384u
#define FB_QF     16400u
#define FB_CTXX   18432u                   // bf16 [256][16][1024] (uses half)
#define FB_CTXP   4212736u
#define FB_POOLP  4737024u
#define FB_LNO    5261312u
#define FB_VTP    5523456u
#define FB_FLOATS 5785600u

typedef __attribute__((ext_vector_type(8))) short short8v;
typedef __attribute__((ext_vector_type(4))) float float4v;

// LDS-only barrier: drains ds ops but leaves global loads in flight.
__device__ __forceinline__ void bar_lds() {
    asm volatile("s_waitcnt lgkmcnt(0)\n\ts_barrier" ::: "memory");
}

// LDS bank swizzle (ushort units, 16B granularity): col ^= (row&7)<<3
#define SW(R, C) ((C) ^ (((R) & 7) << 3))

// ---------------- K0: fused q-prep (block h: qf slice -> qwt row + qbs) ----
__global__ __launch_bounds__(256) void k_qprep(const float* __restrict__ probe,
                                               const float* __restrict__ wq,
                                               const float* __restrict__ bq,
                                               const float* __restrict__ wk,
                                               const float* __restrict__ bk,
                                               float* __restrict__ qwt_hd,
                                               float* __restrict__ qbs) {
    __shared__ float qf_s[64];
    const int h = blockIdx.x, tid = threadIdx.x;
    {   // qf[e] for e = h*64 + (tid>>2); 4 threads per e
        const int e0 = tid >> 2, part = tid & 3;
        const int e = h * 64 + e0;
        const float* wr = wq + (size_t)e * 1024 + part * 256;
        const float* pr = probe + part * 256;
        float s = 0.f;
        for (int k = 0; k < 256; k += 4) {
            float4 a = *(const float4*)(pr + k);
            float4 b = *(const float4*)(wr + k);
            s += a.x * b.x + a.y * b.y + a.z * b.z + a.w * b.w;
        }
        s += __shfl_xor(s, 1); s += __shfl_xor(s, 2);
        if (part == 0) qf_s[e0] = s + bq[e];
    }
    __syncthreads();
    // qwt_hd[h][d] = (1/8) * sum_e qf[e] * wk[e][d]
#pragma unroll
    for (int i = 0; i < 4; ++i) {
        int d = tid + i * 256;
        float s = 0.f;
        for (int e0 = 0; e0 < 64; ++e0)
            s += qf_s[e0] * wk[(size_t)(h * 64 + e0) * 1024 + d];
        qwt_hd[h * 1024 + d] = s * 0.125f;
    }
    if (tid < 64) {
        float p = qf_s[tid] * bk[h * 64 + tid];
        p += __shfl_xor(p, 1);  p += __shfl_xor(p, 2);  p += __shfl_xor(p, 4);
        p += __shfl_xor(p, 8);  p += __shfl_xor(p, 16); p += __shfl_xor(p, 32);
        if (tid == 0) qbs[h] = p * 0.125f;
    }
}

// ---------------- bf16 pack helpers (RNE) ----------------
__device__ __forceinline__ unsigned bf_rne(float f) {
    unsigned u = __float_as_uint(f);
    return (u + 0x7FFFu + ((u >> 16) & 1u)) >> 16;
}
__device__ __forceinline__ uint2 pack_bf4(float4 v) {
    uint2 r;
    r.x = bf_rne(v.x) | (bf_rne(v.y) << 16);
    r.y = bf_rne(v.z) | (bf_rne(v.w) << 16);
    return r;
}

// ---------------- K1: MFMA scores + vector PV, 512 threads, swizzled LDS ----
// 512 threads (8 waves), one (b,t) per block, 16-row chunks (16 chunks).
// LDS (bf16, XOR-swizzled): xbf[16][1056] 33KB single-buffer (reg-prefetch
// st[8], issued BEFORE post-stage barrier), qwbf[16][1056] 33KB resident,
// part[8][16][16] f32, p_lds[16][16] f32.
// Scores: all 8 waves, wave w = k-steps w*4..+3 of mfma_f32_16x16x32_bf16.
// exp: tid<256. PV: thread=(hq=tid>>7, cc=tid&127), acc[8]. l: tid<16.
// Output ctxx in bf16.
__global__ __launch_bounds__(512, 2) void k1_attn(const float* __restrict__ x,
                                                  const float* __restrict__ qwt_hd,
                                                  const float* __restrict__ qbs,
                                                  float* __restrict__ ctxx) {
    __shared__ __align__(16) unsigned short xbf[16][1056];   // 33 KB
    __shared__ __align__(16) unsigned short qwbf[16][1056];  // 33 KB
    __shared__ __align__(16) float part[8][16][16];          // 8 KB
    __shared__ __align__(16) float p_lds[16][16];            // 1 KB
    __shared__ float qb_lds[16];
    __shared__ float linv_lds[16];

    const int tid  = threadIdx.x;
    const int lane = tid & 63;
    const int w    = tid >> 6;          // wave 0..7
    const int hq   = tid >> 7;          // 0..3: heads hq*4..+3 in PV
    const int cc   = tid & 127;         // col-pair: f4-cols 2cc, 2cc+1
    const int bt   = blockIdx.x;
    const float* xb = x + (size_t)bt * 262144;

    // stage qwt (f32 h-major) -> bf16 swizzled LDS, 8 float4/thread
#pragma unroll
    for (int i = 0; i < 8; ++i) {
        int f4i = tid + i * 512;        // 0..4095
        int hr = f4i >> 8, col4 = f4i & 255;
        float4 v = *(const float4*)(qwt_hd + hr * 1024 + col4 * 4);
        *(uint2*)&qwbf[hr][SW(hr, col4 * 4)] = pack_bf4(v);
    }
    if (tid < 16) qb_lds[tid] = qbs[tid];

    float lacc = 0.f;                   // meaningful for tid<16
    float4 acc[8];
#pragma unroll
    for (int i = 0; i < 8; ++i) acc[i] = make_float4(0.f, 0.f, 0.f, 0.f);

    // prologue: chunk 0 (16 rows = 4096 float4), 8 f4/thread
    float4 st[8];
#pragma unroll
    for (int i = 0; i < 8; ++i)
        st[i] = *(const float4*)(xb + (size_t)(tid + i * 512) * 4);

    for (int c = 0; c < 16; ++c) {
        bar_lds();                      // B_a: prev PV done reading xbf
#pragma unroll
        for (int i = 0; i < 8; ++i) {
            int f4i = tid + i * 512;
            int r = f4i >> 8, col4 = f4i & 255;
            *(uint2*)&xbf[r][SW(r, col4 * 4)] = pack_bf4(st[i]);
        }
        if (c < 15) {                   // early prefetch: before B_b
            const float* nb = xb + (size_t)(c + 1) * 16384;
#pragma unroll
            for (int i = 0; i < 8; ++i)
                st[i] = *(const float4*)(nb + (size_t)(tid + i * 512) * 4);
        }
        bar_lds();                      // B_b: xbf (and, at c=0, qwbf) staged
        // ---- scores: all 8 waves, MFMA over K-slices ----
        {
            const int row = lane & 15;      // A row (s) / B row (h)
            const int g   = lane >> 4;      // k-subgroup
            float4v cfr = {0.f, 0.f, 0.f, 0.f};
#pragma unroll
            for (int ks = 0; ks < 4; ++ks) {
                const int koff = (w * 4 + ks) * 32 + g * 8;
                short8v afr = *(const short8v*)&xbf[row][SW(row, koff)];
                short8v bfr = *(const short8v*)&qwbf[row][SW(row, koff)];
                cfr = __builtin_amdgcn_mfma_f32_16x16x32_bf16(afr, bfr, cfr, 0, 0, 0);
            }
#pragma unroll
            for (int r2 = 0; r2 < 4; ++r2)
                part[w][(lane >> 4) * 4 + r2][lane & 15] = cfr[r2];
        }
        bar_lds();                      // B_c: partials ready
        if (tid < 256) {
            int s = tid >> 4, h = tid & 15;
            float sc = 0.f;
#pragma unroll
            for (int pw = 0; pw < 8; ++pw) sc += part[pw][s][h];
            // scores ~|0.05| -> exp with shift 0 numerically safe here
            p_lds[s][h] = __expf(sc + qb_lds[h]);
        }
        bar_lds();                      // B_d: p ready
        if (tid < 16) {                 // l-partials (read-only on p_lds)
            float ll = 0.f;
#pragma unroll
            for (int s = 0; s < 16; ++s) ll += p_lds[s][tid];
            lacc += ll;
        }
        // ---- PV: 16 rows, 4 heads x 2 f4-cols per thread ----
#pragma unroll
        for (int r = 0; r < 16; ++r) {
            uint4 xv = *(const uint4*)&xbf[r][SW(r, cc * 8)];
            float x0 = __uint_as_float(xv.x << 16);
            float x1 = __uint_as_float(xv.x & 0xFFFF0000u);
            float x2 = __uint_as_float(xv.y << 16);
            float x3 = __uint_as_float(xv.y & 0xFFFF0000u);
            float x4 = __uint_as_float(xv.z << 16);
            float x5 = __uint_as_float(xv.z & 0xFFFF0000u);
            float x6 = __uint_as_float(xv.w << 16);
            float x7 = __uint_as_float(xv.w & 0xFFFF0000u);
            float4 p4 = *(const float4*)&p_lds[r][hq * 4];
            acc[0].x += p4.x * x0; acc[0].y += p4.x * x1; acc[0].z += p4.x * x2; acc[0].w += p4.x * x3;
            acc[1].x += p4.y * x0; acc[1].y += p4.y * x1; acc[1].z += p4.y * x2; acc[1].w += p4.y * x3;
            acc[2].x += p4.z * x0; acc[2].y += p4.z * x1; acc[2].z += p4.z * x2; acc[2].w += p4.z * x3;
            acc[3].x += p4.w * x0; acc[3].y += p4.w * x1; acc[3].z += p4.w * x2; acc[3].w += p4.w * x3;
            acc[4].x += p4.x * x4; acc[4].y += p4.x * x5; acc[4].z += p4.x * x6; acc[4].w += p4.x * x7;
            acc[5].x += p4.y * x4; acc[5].y += p4.y * x5; acc[5].z += p4.y * x6; acc[5].w += p4.y * x7;
            acc[6].x += p4.z * x4; acc[6].y += p4.z * x5; acc[6].z += p4.z * x6; acc[6].w += p4.z * x7;
            acc[7].x += p4.w * x4; acc[7].y += p4.w * x5; acc[7].z += p4.w * x6; acc[7].w += p4.w * x7;
        }
    }

    bar_lds();
    if (tid < 16) linv_lds[tid] = 1.0f / lacc;
    bar_lds();
    unsigned short* ob = (unsigned short*)ctxx + (size_t)bt * 16384;
#pragma unroll
    for (int i = 0; i < 4; ++i) {
        float li = linv_lds[hq * 4 + i];
        float4 o0 = acc[i];
        float4 o1 = acc[4 + i];
        o0.x *= li; o0.y *= li; o0.z *= li; o0.w *= li;
        o1.x *= li; o1.y *= li; o1.z *= li; o1.w *= li;
        uint2 p0 = pack_bf4(o0);
        uint2 p1 = pack_bf4(o1);
        uint4 pk = make_uint4(p0.x, p0.y, p1.x, p1.y);
        *(uint4*)(ob + (hq * 4 + i) * 1024 + cc * 8) = pk;
    }
}

// ---------------- K-split GEMM: outp[ks][r][e] = A_row(r)[koff:+512] . B[e, koff:+512] ----
// tile 16 rows x 64 cols, 256 threads, K-slice 512 (8 kc-steps of 64).
// FOLD=0: A_eff = A0 ; FOLD=1: A_eff = A0 + A1 + biask
// ABF16=1: A0 holds bf16 elements (same element indexing)
template<int FOLD, int ABF16>
__global__ __launch_bounds__(256, 2) void k_gemm2(const float* __restrict__ A0,
                                                  const float* __restrict__ A1,
                                                  const float* __restrict__ biask,
                                                  const float* __restrict__ Bw,
                                                  float* __restrict__ outp,
                                                  unsigned a_rstride, unsigned a_cstride,
                                                  unsigned ostride) {
    __shared__ __align__(16) float a_s[16][68];
    __shared__ __align__(16) float b_s[64][68];   // col-f4 swizzled: cs=(k4+e/4)&15
    const int tid = threadIdx.x;
    const int rc = blockIdx.x;     // row-chunk (16 rows)
    const int cb = blockIdx.y;     // col-block (64 cols)
    const int ks = blockIdx.z;     // K-split 0,1
    const int koff = ks * 512;
    const int rr = tid >> 4;       // output row 0..15
    const int ee = tid & 15;       // output cols ee*4..+3

    const size_t abase = (size_t)(rc * 16 + rr) * a_rstride + (size_t)cb * a_cstride + koff;

    float ac0 = 0.f, ac1 = 0.f, ac2 = 0.f, ac3 = 0.f;

    for (int kc = 0; kc < 8; ++kc) {
        __syncthreads();
        {   // stage A: 1 float4/thread (bf16 unpack if ABF16)
            float4 av;
            if (ABF16) {
                const unsigned short* A0h = (const unsigned short*)A0;
                uint2 u = *(const uint2*)(A0h + abase + kc * 64 + ee * 4);
                av.x = __uint_as_float(u.x << 16);
                av.y = __uint_as_float(u.x & 0xFFFF0000u);
                av.z = __uint_as_float(u.y << 16);
                av.w = __uint_as_float(u.y & 0xFFFF0000u);
            } else {
                av = *(const float4*)(A0 + abase + kc * 64 + ee * 4);
            }
            if (FOLD == 1) {
                float4 a1v = *(const float4*)(A1 + abase + kc * 64 + ee * 4);
                float4 bk4 = *(const float4*)(biask + koff + kc * 64 + ee * 4);
                av.x += a1v.x + bk4.x; av.y += a1v.y + bk4.y;
                av.z += a1v.z + bk4.z; av.w += a1v.w + bk4.w;
            }
            *(float4*)&a_s[rr][ee * 4] = av;
        }
        // stage B: 4 float4/thread, linear global -> swizzled LDS
#pragma unroll
        for (int i = 0; i < 4; ++i) {
            int f4i = tid + i * 256;
            int e = f4i >> 4, k4 = f4i & 15;
            float4 bv4 = *(const float4*)(Bw + (size_t)(cb * 64 + e) * 1024 + koff + kc * 64 + k4 * 4);
            int cs = (k4 + (e >> 2)) & 15;
            *(float4*)&b_s[e][cs * 4] = bv4;
        }
        __syncthreads();
#pragma unroll
        for (int k4 = 0; k4 < 16; ++k4) {
            float4 av = *(const float4*)&a_s[rr][k4 * 4];
            int cs = (k4 + ee) & 15;
            float4 b0 = *(const float4*)&b_s[ee * 4 + 0][cs * 4];
            float4 b1 = *(const float4*)&b_s[ee * 4 + 1][cs * 4];
            float4 b2 = *(const float4*)&b_s[ee * 4 + 2][cs * 4];
            float4 b3 = *(const float4*)&b_s[ee * 4 + 3][cs * 4];
            ac0 += av.x * b0.x + av.y * b0.y + av.z * b0.z + av.w * b0.w;
            ac1 += av.x * b1.x + av.y * b1.y + av.z * b1.z + av.w * b1.w;
            ac2 += av.x * b2.x + av.y * b2.y + av.z * b2.z + av.w * b2.w;
            ac3 += av.x * b3.x + av.y * b3.y + av.z * b3.z + av.w * b3.w;
        }
    }
    float4 o = make_float4(ac0, ac1, ac2, ac3);
    *(float4*)(outp + (size_t)ks * 256 * ostride + (size_t)(rc * 16 + rr) * ostride + cb * 64 + ee * 4) = o;
}

// ---------------- LayerNorm over D=1024, folds poolp0+poolp1+bo ----------------
__global__ __launch_bounds__(256) void k_ln(const float* __restrict__ poolp,
                                            const float* __restrict__ bo,
                                            const float* __restrict__ g,
                                            const float* __restrict__ bb,
                                            float* __restrict__ out) {
    __shared__ float sm[8];
    int row = blockIdx.x, tid = threadIdx.x;
    float4 v0 = *(const float4*)(poolp + (size_t)row * 1024 + tid * 4);
    float4 v1 = *(const float4*)(poolp + 262144u + (size_t)row * 1024 + tid * 4);
    float4 bv = *(const float4*)(bo + tid * 4);
    float4 v;
    v.x = v0.x + v1.x + bv.x; v.y = v0.y + v1.y + bv.y;
    v.z = v0.z + v1.z + bv.z; v.w = v0.w + v1.w + bv.w;
    float s = v.x + v.y + v.z + v.w;
    float q = v.x * v.x + v.y * v.y + v.z * v.z + v.w * v.w;
    s += __shfl_xor(s, 1);  q += __shfl_xor(q, 1);
    s += __shfl_xor(s, 2);  q += __shfl_xor(q, 2);
    s += __shfl_xor(s, 4);  q += __shfl_xor(q, 4);
    s += __shfl_xor(s, 8);  q += __shfl_xor(q, 8);
    s += __shfl_xor(s, 16); q += __shfl_xor(q, 16);
    s += __shfl_xor(s, 32); q += __shfl_xor(q, 32);
    if ((tid & 63) == 0) { sm[tid >> 6] = s; sm[4 + (tid >> 6)] = q; }
    __syncthreads();
    float S = sm[0] + sm[1] + sm[2] + sm[3];
    float Q = sm[4] + sm[5] + sm[6] + sm[7];
    float mu = S * (1.f / 1024.f);
    float var = Q * (1.f / 1024.f) - mu * mu;
    float rs = rsqrtf(var + 1e-6f);
    float4 gg = *(const float4*)(g + tid * 4);
    float4 be = *(const float4*)(bb + tid * 4);
    float4 o;
    o.x = (v.x - mu) * rs * gg.x + be.x;
    o.y = (v.y - mu) * rs * gg.y + be.y;
    o.z = (v.z - mu) * rs * gg.z + be.z;
    o.w = (v.w - mu) * rs * gg.w + be.w;
    *(float4*)(out + (size_t)row * 1024 + tid * 4) = o;
}

// ---------------- sim = (vt_hat . a_hat) * exp(ls) + lb ----------------
// folds vtp0+vtp1+pb; block: 32 vt rows x 64 audio rows; grid (32,8)
__global__ __launch_bounds__(256, 2) void k_sim(const float* __restrict__ vtp,
                                                const float* __restrict__ pb,
                                                const float* __restrict__ audio,
                                                const float* __restrict__ ls,
                                                const float* __restrict__ lb,
                                                float* __restrict__ out) {
    __shared__ float a_s[64][65];
    __shared__ float v_s[32][65];
    __shared__ float rinv_a[64];
    __shared__ float rinv_v[32];
    const int tid = threadIdx.x;
    const int lc = blockIdx.x;   // 0..31
    const int b  = blockIdx.y;   // 0..7
    const int al = tid >> 2, ak = (tid & 3) * 16;
    const int vl = tid >> 3, vk = (tid & 7) * 8;
    const int rg = tid >> 4, lg = tid & 15;
    float ssa = 0.f, ssv = 0.f;
    float c00=0,c01=0,c02=0,c03=0,c10=0,c11=0,c12=0,c13=0;

    for (int kc = 0; kc < 8; ++kc) {
        __syncthreads();
        {
            const float* ap = audio + (size_t)b * 1048576 + (size_t)(lc * 64 + al) * 512 + kc * 64 + ak;
#pragma unroll
            for (int i = 0; i < 4; ++i) {
                float4 wv4 = *(const float4*)(ap + i * 4);
                ssa += wv4.x * wv4.x + wv4.y * wv4.y + wv4.z * wv4.z + wv4.w * wv4.w;
                a_s[al][ak + i * 4 + 0] = wv4.x; a_s[al][ak + i * 4 + 1] = wv4.y;
                a_s[al][ak + i * 4 + 2] = wv4.z; a_s[al][ak + i * 4 + 3] = wv4.w;
            }
            const size_t voff = (size_t)(b * 32 + vl) * 512 + kc * 64 + vk;
#pragma unroll
            for (int i = 0; i < 2; ++i) {
                float4 p0 = *(const float4*)(vtp + voff + i * 4);
                float4 p1 = *(const float4*)(vtp + 131072u + voff + i * 4);
                float4 pbv = *(const float4*)(pb + kc * 64 + vk + i * 4);
                float4 wv4;
                wv4.x = p0.x + p1.x + pbv.x; wv4.y = p0.y + p1.y + pbv.y;
                wv4.z = p0.z + p1.z + pbv.z; wv4.w = p0.w + p1.w + pbv.w;
                ssv += wv4.x * wv4.x + wv4.y * wv4.y + wv4.z * wv4.z + wv4.w * wv4.w;
                v_s[vl][vk + i * 4 + 0] = wv4.x; v_s[vl][vk + i * 4 + 1] = wv4.y;
                v_s[vl][vk + i * 4 + 2] = wv4.z; v_s[vl][vk + i * 4 + 3] = wv4.w;
            }
        }
        __syncthreads();
#pragma unroll 2
        for (int k = 0; k < 64; ++k) {
            float v0 = v_s[rg * 2 + 0][k];
            float v1 = v_s[rg * 2 + 1][k];
            float x0 = a_s[lg * 4 + 0][k];
            float x1 = a_s[lg * 4 + 1][k];
            float x2 = a_s[lg * 4 + 2][k];
            float x3 = a_s[lg * 4 + 3][k];
            c00 += v0 * x0; c01 += v0 * x1; c02 += v0 * x2; c03 += v0 * x3;
            c10 += v1 * x0; c11 += v1 * x1; c12 += v1 * x2; c13 += v1 * x3;
        }
    }
    ssa += __shfl_xor(ssa, 1); ssa += __shfl_xor(ssa, 2);
    if ((tid & 3) == 0) rinv_a[al] = rsqrtf(ssa);
    ssv += __shfl_xor(ssv, 1); ssv += __shfl_xor(ssv, 2); ssv += __shfl_xor(ssv, 4);
    if ((tid & 7) == 0) rinv_v[vl] = rsqrtf(ssv);
    __syncthreads();
    const float sc = __expf(ls[0]);
    const float bias = lb[0];
    float ra0 = rinv_a[lg * 4 + 0], ra1 = rinv_a[lg * 4 + 1];
    float ra2 = rinv_a[lg * 4 + 2], ra3 = rinv_a[lg * 4 + 3];
    float accs[2][4] = {{c00,c01,c02,c03},{c10,c11,c12,c13}};
#pragma unroll
    for (int cr = 0; cr < 2; ++cr) {
        int t = rg * 2 + cr;
        float rv = rinv_v[t] * sc;
        float4 o;
        o.x = accs[cr][0] * rv * ra0 + bias;
        o.y = accs[cr][1] * rv * ra1 + bias;
        o.z = accs[cr][2] * rv * ra2 + bias;
        o.w = accs[cr][3] * rv * ra3 + bias;
        *(float4*)(out + (size_t)b * 65536 + (size_t)t * 2048 + lc * 64 + lg * 4) = o;
    }
}

// ---------------- launch ----------------
extern "C" void kernel_launch(void* const* d_in, const int* in_sizes, int n_in,
                              void* d_out, int out_size, void* d_ws, size_t ws_size,
                              hipStream_t stream) {
    (void)in_sizes; (void)n_in; (void)out_size;
    const float* video = (const float*)d_in[0];
    const float* audio = (const float*)d_in[1];
    const float* probe = (const float*)d_in[2];
    const float* wq    = (const float*)d_in[3];
    const float* wk    = (const float*)d_in[4];
    const float* wv    = (const float*)d_in[5];
    const float* bq    = (const float*)d_in[6];
    const float* bk    = (const float*)d_in[7];
    const float* bv    = (const float*)d_in[8];
    const float* wo    = (const float*)d_in[9];
    const float* bo    = (const float*)d_in[10];
    const float* lng   = (const float*)d_in[11];
    const float* lnb   = (const float*)d_in[12];
    const float* pw    = (const float*)d_in[13];
    const float* pb    = (const float*)d_in[14];
    const float* ls    = (const float*)d_in[15];
    const float* lb    = (const float*)d_in[16];
    float* ws  = (float*)d_ws;
    float* out = (float*)d_out;
    if (ws_size < FB_FLOATS * sizeof(float)) return;

    float* qwt  = ws + FB_QWT;   // [16][1024] h-major
    float* qbs  = ws + FB_QB;
    float* ctxx = ws + FB_CTXX;  // bf16 payload
    float* ctxp = ws + FB_CTXP;
    float* poolp= ws + FB_POOLP;
    float* lno  = ws + FB_LNO;
    float* vtp  = ws + FB_VTP;

    k_qprep<<<dim3(16), dim3(256), 0, stream>>>(probe, wq, bq, wk, bk, qwt, qbs);
    k1_attn<<<dim3(256), dim3(512), 0, stream>>>(video, qwt, qbs, ctxx);
    // G1: ctxx_bf16 (head-block diagonal) @ wv^T -> ctxp  [K=1024 split 2]
    k_gemm2<0, 1><<<dim3(16, 16, 2), dim3(256), 0, stream>>>(ctxx, nullptr, nullptr, wv, ctxp,
                                                             16384u, 1024u, 1024u);
    // G2: (ctxp0+ctxp1+bv) @ wo^T -> poolp                [K=1024 split 2]
    k_gemm2<1, 0><<<dim3(16, 16, 2), dim3(256), 0, stream>>>(ctxp, ctxp + 262144u, bv, wo, poolp,
                                                             1024u, 0u, 1024u);
    k_ln<<<dim3(256), dim3(256), 0, stream>>>(poolp, bo, lng, lnb, lno);
    // G3: lno @ pw^T -> vtp                               [K=1024 split 2]
    k_gemm2<0, 0><<<dim3(16, 8, 2), dim3(256), 0, stream>>>(lno, nullptr, nullptr, pw, vtp,
                                                            1024u, 0u, 512u);
    k_sim<<<dim3(32, 8), dim3(256), 0, stream>>>(vtp, pb, audio, ls, lb, out);
}

// Round 19
// 172.904 us; speedup vs baseline: 1.3319x; 1.3319x over previous
//
#include <hip/hip_runtime.h>

// ---------------- problem constants ----------------
// B=8, T=32, S=256, DV=1024, NH=16, dh=64, DA=512, L2=2048
// video_x: [8, 8192, 1024] f32   audio_x: [8, 2048, 512] f32
// out: [8, 32, 2048] f32
//
// MEASURED (R3-R18):
//  * 512-thr/(512,2) = no spill; R15+early-prefetch = 173us (best).
//  * R18 bundled {LDS swizzle, bf16 ctxx, 16-block k_qprep} -> 230us.
//    Arithmetic points at k_qprep (16 blocks = 16 CUs, latency-bound
//    rolled loops, ~+50us). This round unbundles: restore full-parallel
//    k_qflat+k_qwt, KEEP swizzle (unswizzled MFMA reads = 8-way conflict,
//    row stride 2112B = 64 mod 128) and bf16 ctxx (absmax-proven).
//
// Pipeline (f32 except bf16 MFMA operands + bf16 ctxx):
//  qf = probe@wqT+bq ; qwt_hd[h][d] = (1/8)*sum_{e in h} qf[e]*wk[e][d] ; qbs[h]
//  k1: S=x_bf@qw_bf^T (MFMA); p=exp(S+qb); ctxx_bf16[h][d]=sum_s p*x /l
//  G1: ctx = ctxx_bf16(head-block) @ wv^T         (K-split 2 -> ctxp)
//  G2: pool = (ctxp0+ctxp1+bv) @ wo^T             (K-split 2 -> poolp)
//  LN: lno = LN(poolp0+poolp1+bo)
//  G3: vt = lno @ pw^T                            (K-split 2 -> vtp)
//  sim: (norm(vtp0+vtp1+pb) . norm(audio)) * exp(ls) + lb

// ---- ws layout (float offsets; CTXX region holds bf16, oversized) ----
#define FB_QWT    0u                       // [16][1024]  (h-major)
#define FB_QB     16384u
#define FB_QF     16400u
#define FB_CTXX   18432u                   // bf16 [256][16][1024] (uses half)
#define FB_CTXP   4212736u
#define FB_POOLP  4737024u
#define FB_LNO    5261312u
#define FB_VTP    5523456u
#define FB_FLOATS 5785600u

typedef __attribute__((ext_vector_type(8))) short short8v;
typedef __attribute__((ext_vector_type(4))) float float4v;

// LDS-only barrier: drains ds ops but leaves global loads in flight.
__device__ __forceinline__ void bar_lds() {
    asm volatile("s_waitcnt lgkmcnt(0)\n\ts_barrier" ::: "memory");
}

// LDS bank swizzle (ushort units, 16B granularity): col ^= (row&7)<<3
#define SW(R, C) ((C) ^ (((R) & 7) << 3))

// ---------------- K0a: q_flat[e] = probe . wq[e,:] + bq[e] ----------------
__global__ __launch_bounds__(256) void k_qflat(const float* __restrict__ probe,
                                               const float* __restrict__ wq,
                                               const float* __restrict__ bq,
                                               float* __restrict__ qf) {
    int e = blockIdx.x, tid = threadIdx.x;
    const float* wr = wq + (size_t)e * 1024;
    float s = 0.f;
    for (int k = tid; k < 1024; k += 256) s += probe[k] * wr[k];
    s += __shfl_xor(s, 1);  s += __shfl_xor(s, 2);  s += __shfl_xor(s, 4);
    s += __shfl_xor(s, 8);  s += __shfl_xor(s, 16); s += __shfl_xor(s, 32);
    __shared__ float sm[4];
    if ((tid & 63) == 0) sm[tid >> 6] = s;
    __syncthreads();
    if (tid == 0) qf[e] = sm[0] + sm[1] + sm[2] + sm[3] + bq[e];
}

// ---------------- K0b: qwt_hd[h][d] = (1/8) * sum_{e in h} qf[e]*wk[e][d] ----------------
__global__ __launch_bounds__(64) void k_qwt(const float* __restrict__ qf,
                                            const float* __restrict__ wk,
                                            const float* __restrict__ bk,
                                            float* __restrict__ qwt_hd,
                                            float* __restrict__ qbs) {
    int kc = blockIdx.x, h = blockIdx.y, tid = threadIdx.x; // 64 threads = 1 wave
    int d = kc * 64 + tid;
    float s = 0.f;
    for (int e0 = 0; e0 < 64; ++e0) {
        int e = h * 64 + e0;
        s += qf[e] * wk[(size_t)e * 1024 + d];
    }
    qwt_hd[h * 1024 + d] = s * 0.125f;      // h-major layout
    if (kc == 0) {
        float p = qf[h * 64 + tid] * bk[h * 64 + tid];
        p += __shfl_xor(p, 1);  p += __shfl_xor(p, 2);  p += __shfl_xor(p, 4);
        p += __shfl_xor(p, 8);  p += __shfl_xor(p, 16); p += __shfl_xor(p, 32);
        if (tid == 0) qbs[h] = p * 0.125f;
    }
}

// ---------------- bf16 pack helpers (RNE) ----------------
__device__ __forceinline__ unsigned bf_rne(float f) {
    unsigned u = __float_as_uint(f);
    return (u + 0x7FFFu + ((u >> 16) & 1u)) >> 16;
}
__device__ __forceinline__ uint2 pack_bf4(float4 v) {
    uint2 r;
    r.x = bf_rne(v.x) | (bf_rne(v.y) << 16);
    r.y = bf_rne(v.z) | (bf_rne(v.w) << 16);
    return r;
}

// ---------------- K1: MFMA scores + vector PV, 512 threads, swizzled LDS ----
// 512 threads (8 waves), one (b,t) per block, 16-row chunks (16 chunks).
// LDS (bf16, XOR-swizzled): xbf[16][1056] 33KB single-buffer (reg-prefetch
// st[8], issued BEFORE post-stage barrier), qwbf[16][1056] 33KB resident,
// part[8][16][16] f32, p_lds[16][16] f32.
// Scores: all 8 waves, wave w = k-steps w*4..+3 of mfma_f32_16x16x32_bf16.
// exp: tid<256. PV: thread=(hq=tid>>7, cc=tid&127), acc[8]. l: tid<16.
// Output ctxx in bf16.
__global__ __launch_bounds__(512, 2) void k1_attn(const float* __restrict__ x,
                                                  const float* __restrict__ qwt_hd,
                                                  const float* __restrict__ qbs,
                                                  float* __restrict__ ctxx) {
    __shared__ __align__(16) unsigned short xbf[16][1056];   // 33 KB
    __shared__ __align__(16) unsigned short qwbf[16][1056];  // 33 KB
    __shared__ __align__(16) float part[8][16][16];          // 8 KB
    __shared__ __align__(16) float p_lds[16][16];            // 1 KB
    __shared__ float qb_lds[16];
    __shared__ float linv_lds[16];

    const int tid  = threadIdx.x;
    const int lane = tid & 63;
    const int w    = tid >> 6;          // wave 0..7
    const int hq   = tid >> 7;          // 0..3: heads hq*4..+3 in PV
    const int cc   = tid & 127;         // col-pair: f4-cols 2cc, 2cc+1
    const int bt   = blockIdx.x;
    const float* xb = x + (size_t)bt * 262144;

    // stage qwt (f32 h-major) -> bf16 swizzled LDS, 8 float4/thread
#pragma unroll
    for (int i = 0; i < 8; ++i) {
        int f4i = tid + i * 512;        // 0..4095
        int hr = f4i >> 8, col4 = f4i & 255;
        float4 v = *(const float4*)(qwt_hd + hr * 1024 + col4 * 4);
        *(uint2*)&qwbf[hr][SW(hr, col4 * 4)] = pack_bf4(v);
    }
    if (tid < 16) qb_lds[tid] = qbs[tid];

    float lacc = 0.f;                   // meaningful for tid<16
    float4 acc[8];
#pragma unroll
    for (int i = 0; i < 8; ++i) acc[i] = make_float4(0.f, 0.f, 0.f, 0.f);

    // prologue: chunk 0 (16 rows = 4096 float4), 8 f4/thread
    float4 st[8];
#pragma unroll
    for (int i = 0; i < 8; ++i)
        st[i] = *(const float4*)(xb + (size_t)(tid + i * 512) * 4);

    for (int c = 0; c < 16; ++c) {
        bar_lds();                      // B_a: prev PV done reading xbf
#pragma unroll
        for (int i = 0; i < 8; ++i) {
            int f4i = tid + i * 512;
            int r = f4i >> 8, col4 = f4i & 255;
            *(uint2*)&xbf[r][SW(r, col4 * 4)] = pack_bf4(st[i]);
        }
        if (c < 15) {                   // early prefetch: before B_b
            const float* nb = xb + (size_t)(c + 1) * 16384;
#pragma unroll
            for (int i = 0; i < 8; ++i)
                st[i] = *(const float4*)(nb + (size_t)(tid + i * 512) * 4);
        }
        bar_lds();                      // B_b: xbf (and, at c=0, qwbf) staged
        // ---- scores: all 8 waves, MFMA over K-slices ----
        {
            const int row = lane & 15;      // A row (s) / B row (h)
            const int g   = lane >> 4;      // k-subgroup
            float4v cfr = {0.f, 0.f, 0.f, 0.f};
#pragma unroll
            for (int ks = 0; ks < 4; ++ks) {
                const int koff = (w * 4 + ks) * 32 + g * 8;
                short8v afr = *(const short8v*)&xbf[row][SW(row, koff)];
                short8v bfr = *(const short8v*)&qwbf[row][SW(row, koff)];
                cfr = __builtin_amdgcn_mfma_f32_16x16x32_bf16(afr, bfr, cfr, 0, 0, 0);
            }
#pragma unroll
            for (int r2 = 0; r2 < 4; ++r2)
                part[w][(lane >> 4) * 4 + r2][lane & 15] = cfr[r2];
        }
        bar_lds();                      // B_c: partials ready
        if (tid < 256) {
            int s = tid >> 4, h = tid & 15;
            float sc = 0.f;
#pragma unroll
            for (int pw = 0; pw < 8; ++pw) sc += part[pw][s][h];
            // scores ~|0.05| -> exp with shift 0 numerically safe here
            p_lds[s][h] = __expf(sc + qb_lds[h]);
        }
        bar_lds();                      // B_d: p ready
        if (tid < 16) {                 // l-partials (read-only on p_lds)
            float ll = 0.f;
#pragma unroll
            for (int s = 0; s < 16; ++s) ll += p_lds[s][tid];
            lacc += ll;
        }
        // ---- PV: 16 rows, 4 heads x 2 f4-cols per thread ----
#pragma unroll
        for (int r = 0; r < 16; ++r) {
            uint4 xv = *(const uint4*)&xbf[r][SW(r, cc * 8)];
            float x0 = __uint_as_float(xv.x << 16);
            float x1 = __uint_as_float(xv.x & 0xFFFF0000u);
            float x2 = __uint_as_float(xv.y << 16);
            float x3 = __uint_as_float(xv.y & 0xFFFF0000u);
            float x4 = __uint_as_float(xv.z << 16);
            float x5 = __uint_as_float(xv.z & 0xFFFF0000u);
            float x6 = __uint_as_float(xv.w << 16);
            float x7 = __uint_as_float(xv.w & 0xFFFF0000u);
            float4 p4 = *(const float4*)&p_lds[r][hq * 4];
            acc[0].x += p4.x * x0; acc[0].y += p4.x * x1; acc[0].z += p4.x * x2; acc[0].w += p4.x * x3;
            acc[1].x += p4.y * x0; acc[1].y += p4.y * x1; acc[1].z += p4.y * x2; acc[1].w += p4.y * x3;
            acc[2].x += p4.z * x0; acc[2].y += p4.z * x1; acc[2].z += p4.z * x2; acc[2].w += p4.z * x3;
            acc[3].x += p4.w * x0; acc[3].y += p4.w * x1; acc[3].z += p4.w * x2; acc[3].w += p4.w * x3;
            acc[4].x += p4.x * x4; acc[4].y += p4.x * x5; acc[4].z += p4.x * x6; acc[4].w += p4.x * x7;
            acc[5].x += p4.y * x4; acc[5].y += p4.y * x5; acc[5].z += p4.y * x6; acc[5].w += p4.y * x7;
            acc[6].x += p4.z * x4; acc[6].y += p4.z * x5; acc[6].z += p4.z * x6; acc[6].w += p4.z * x7;
            acc[7].x += p4.w * x4; acc[7].y += p4.w * x5; acc[7].z += p4.w * x6; acc[7].w += p4.w * x7;
        }
    }

    bar_lds();
    if (tid < 16) linv_lds[tid] = 1.0f / lacc;
    bar_lds();
    unsigned short* ob = (unsigned short*)ctxx + (size_t)bt * 16384;
#pragma unroll
    for (int i = 0; i < 4; ++i) {
        float li = linv_lds[hq * 4 + i];
        float4 o0 = acc[i];
        float4 o1 = acc[4 + i];
        o0.x *= li; o0.y *= li; o0.z *= li; o0.w *= li;
        o1.x *= li; o1.y *= li; o1.z *= li; o1.w *= li;
        uint2 p0 = pack_bf4(o0);
        uint2 p1 = pack_bf4(o1);
        uint4 pk = make_uint4(p0.x, p0.y, p1.x, p1.y);
        *(uint4*)(ob + (hq * 4 + i) * 1024 + cc * 8) = pk;
    }
}

// ---------------- K-split GEMM: outp[ks][r][e] = A_row(r)[koff:+512] . B[e, koff:+512] ----
// tile 16 rows x 64 cols, 256 threads, K-slice 512 (8 kc-steps of 64).
// FOLD=0: A_eff = A0 ; FOLD=1: A_eff = A0 + A1 + biask
// ABF16=1: A0 holds bf16 elements (same element indexing)
template<int FOLD, int ABF16>
__global__ __launch_bounds__(256, 2) void k_gemm2(const float* __restrict__ A0,
                                                  const float* __restrict__ A1,
                                                  const float* __restrict__ biask,
                                                  const float* __restrict__ Bw,
                                                  float* __restrict__ outp,
                                                  unsigned a_rstride, unsigned a_cstride,
                                                  unsigned ostride) {
    __shared__ __align__(16) float a_s[16][68];
    __shared__ __align__(16) float b_s[64][68];   // col-f4 swizzled: cs=(k4+e/4)&15
    const int tid = threadIdx.x;
    const int rc = blockIdx.x;     // row-chunk (16 rows)
    const int cb = blockIdx.y;     // col-block (64 cols)
    const int ks = blockIdx.z;     // K-split 0,1
    const int koff = ks * 512;
    const int rr = tid >> 4;       // output row 0..15
    const int ee = tid & 15;       // output cols ee*4..+3

    const size_t abase = (size_t)(rc * 16 + rr) * a_rstride + (size_t)cb * a_cstride + koff;

    float ac0 = 0.f, ac1 = 0.f, ac2 = 0.f, ac3 = 0.f;

    for (int kc = 0; kc < 8; ++kc) {
        __syncthreads();
        {   // stage A: 1 float4/thread (bf16 unpack if ABF16)
            float4 av;
            if (ABF16) {
                const unsigned short* A0h = (const unsigned short*)A0;
                uint2 u = *(const uint2*)(A0h + abase + kc * 64 + ee * 4);
                av.x = __uint_as_float(u.x << 16);
                av.y = __uint_as_float(u.x & 0xFFFF0000u);
                av.z = __uint_as_float(u.y << 16);
                av.w = __uint_as_float(u.y & 0xFFFF0000u);
            } else {
                av = *(const float4*)(A0 + abase + kc * 64 + ee * 4);
            }
            if (FOLD == 1) {
                float4 a1v = *(const float4*)(A1 + abase + kc * 64 + ee * 4);
                float4 bk4 = *(const float4*)(biask + koff + kc * 64 + ee * 4);
                av.x += a1v.x + bk4.x; av.y += a1v.y + bk4.y;
                av.z += a1v.z + bk4.z; av.w += a1v.w + bk4.w;
            }
            *(float4*)&a_s[rr][ee * 4] = av;
        }
        // stage B: 4 float4/thread, linear global -> swizzled LDS
#pragma unroll
        for (int i = 0; i < 4; ++i) {
            int f4i = tid + i * 256;
            int e = f4i >> 4, k4 = f4i & 15;
            float4 bv4 = *(const float4*)(Bw + (size_t)(cb * 64 + e) * 1024 + koff + kc * 64 + k4 * 4);
            int cs = (k4 + (e >> 2)) & 15;
            *(float4*)&b_s[e][cs * 4] = bv4;
        }
        __syncthreads();
#pragma unroll
        for (int k4 = 0; k4 < 16; ++k4) {
            float4 av = *(const float4*)&a_s[rr][k4 * 4];
            int cs = (k4 + ee) & 15;
            float4 b0 = *(const float4*)&b_s[ee * 4 + 0][cs * 4];
            float4 b1 = *(const float4*)&b_s[ee * 4 + 1][cs * 4];
            float4 b2 = *(const float4*)&b_s[ee * 4 + 2][cs * 4];
            float4 b3 = *(const float4*)&b_s[ee * 4 + 3][cs * 4];
            ac0 += av.x * b0.x + av.y * b0.y + av.z * b0.z + av.w * b0.w;
            ac1 += av.x * b1.x + av.y * b1.y + av.z * b1.z + av.w * b1.w;
            ac2 += av.x * b2.x + av.y * b2.y + av.z * b2.z + av.w * b2.w;
            ac3 += av.x * b3.x + av.y * b3.y + av.z * b3.z + av.w * b3.w;
        }
    }
    float4 o = make_float4(ac0, ac1, ac2, ac3);
    *(float4*)(outp + (size_t)ks * 256 * ostride + (size_t)(rc * 16 + rr) * ostride + cb * 64 + ee * 4) = o;
}

// ---------------- LayerNorm over D=1024, folds poolp0+poolp1+bo ----------------
__global__ __launch_bounds__(256) void k_ln(const float* __restrict__ poolp,
                                            const float* __restrict__ bo,
                                            const float* __restrict__ g,
                                            const float* __restrict__ bb,
                                            float* __restrict__ out) {
    __shared__ float sm[8];
    int row = blockIdx.x, tid = threadIdx.x;
    float4 v0 = *(const float4*)(poolp + (size_t)row * 1024 + tid * 4);
    float4 v1 = *(const float4*)(poolp + 262144u + (size_t)row * 1024 + tid * 4);
    float4 bv = *(const float4*)(bo + tid * 4);
    float4 v;
    v.x = v0.x + v1.x + bv.x; v.y = v0.y + v1.y + bv.y;
    v.z = v0.z + v1.z + bv.z; v.w = v0.w + v1.w + bv.w;
    float s = v.x + v.y + v.z + v.w;
    float q = v.x * v.x + v.y * v.y + v.z * v.z + v.w * v.w;
    s += __shfl_xor(s, 1);  q += __shfl_xor(q, 1);
    s += __shfl_xor(s, 2);  q += __shfl_xor(q, 2);
    s += __shfl_xor(s, 4);  q += __shfl_xor(q, 4);
    s += __shfl_xor(s, 8);  q += __shfl_xor(q, 8);
    s += __shfl_xor(s, 16); q += __shfl_xor(q, 16);
    s += __shfl_xor(s, 32); q += __shfl_xor(q, 32);
    if ((tid & 63) == 0) { sm[tid >> 6] = s; sm[4 + (tid >> 6)] = q; }
    __syncthreads();
    float S = sm[0] + sm[1] + sm[2] + sm[3];
    float Q = sm[4] + sm[5] + sm[6] + sm[7];
    float mu = S * (1.f / 1024.f);
    float var = Q * (1.f / 1024.f) - mu * mu;
    float rs = rsqrtf(var + 1e-6f);
    float4 gg = *(const float4*)(g + tid * 4);
    float4 be = *(const float4*)(bb + tid * 4);
    float4 o;
    o.x = (v.x - mu) * rs * gg.x + be.x;
    o.y = (v.y - mu) * rs * gg.y + be.y;
    o.z = (v.z - mu) * rs * gg.z + be.z;
    o.w = (v.w - mu) * rs * gg.w + be.w;
    *(float4*)(out + (size_t)row * 1024 + tid * 4) = o;
}

// ---------------- sim = (vt_hat . a_hat) * exp(ls) + lb ----------------
// folds vtp0+vtp1+pb; block: 32 vt rows x 64 audio rows; grid (32,8)
__global__ __launch_bounds__(256, 2) void k_sim(const float* __restrict__ vtp,
                                                const float* __restrict__ pb,
                                                const float* __restrict__ audio,
                                                const float* __restrict__ ls,
                                                const float* __restrict__ lb,
                                                float* __restrict__ out) {
    __shared__ float a_s[64][65];
    __shared__ float v_s[32][65];
    __shared__ float rinv_a[64];
    __shared__ float rinv_v[32];
    const int tid = threadIdx.x;
    const int lc = blockIdx.x;   // 0..31
    const int b  = blockIdx.y;   // 0..7
    const int al = tid >> 2, ak = (tid & 3) * 16;
    const int vl = tid >> 3, vk = (tid & 7) * 8;
    const int rg = tid >> 4, lg = tid & 15;
    float ssa = 0.f, ssv = 0.f;
    float c00=0,c01=0,c02=0,c03=0,c10=0,c11=0,c12=0,c13=0;

    for (int kc = 0; kc < 8; ++kc) {
        __syncthreads();
        {
            const float* ap = audio + (size_t)b * 1048576 + (size_t)(lc * 64 + al) * 512 + kc * 64 + ak;
#pragma unroll
            for (int i = 0; i < 4; ++i) {
                float4 wv4 = *(const float4*)(ap + i * 4);
                ssa += wv4.x * wv4.x + wv4.y * wv4.y + wv4.z * wv4.z + wv4.w * wv4.w;
                a_s[al][ak + i * 4 + 0] = wv4.x; a_s[al][ak + i * 4 + 1] = wv4.y;
                a_s[al][ak + i * 4 + 2] = wv4.z; a_s[al][ak + i * 4 + 3] = wv4.w;
            }
            const size_t voff = (size_t)(b * 32 + vl) * 512 + kc * 64 + vk;
#pragma unroll
            for (int i = 0; i < 2; ++i) {
                float4 p0 = *(const float4*)(vtp + voff + i * 4);
                float4 p1 = *(const float4*)(vtp + 131072u + voff + i * 4);
                float4 pbv = *(const float4*)(pb + kc * 64 + vk + i * 4);
                float4 wv4;
                wv4.x = p0.x + p1.x + pbv.x; wv4.y = p0.y + p1.y + pbv.y;
                wv4.z = p0.z + p1.z + pbv.z; wv4.w = p0.w + p1.w + pbv.w;
                ssv += wv4.x * wv4.x + wv4.y * wv4.y + wv4.z * wv4.z + wv4.w * wv4.w;
                v_s[vl][vk + i * 4 + 0] = wv4.x; v_s[vl][vk + i * 4 + 1] = wv4.y;
                v_s[vl][vk + i * 4 + 2] = wv4.z; v_s[vl][vk + i * 4 + 3] = wv4.w;
            }
        }
        __syncthreads();
#pragma unroll 2
        for (int k = 0; k < 64; ++k) {
            float v0 = v_s[rg * 2 + 0][k];
            float v1 = v_s[rg * 2 + 1][k];
            float x0 = a_s[lg * 4 + 0][k];
            float x1 = a_s[lg * 4 + 1][k];
            float x2 = a_s[lg * 4 + 2][k];
            float x3 = a_s[lg * 4 + 3][k];
            c00 += v0 * x0; c01 += v0 * x1; c02 += v0 * x2; c03 += v0 * x3;
            c10 += v1 * x0; c11 += v1 * x1; c12 += v1 * x2; c13 += v1 * x3;
        }
    }
    ssa += __shfl_xor(ssa, 1); ssa += __shfl_xor(ssa, 2);
    if ((tid & 3) == 0) rinv_a[al] = rsqrtf(ssa);
    ssv += __shfl_xor(ssv, 1); ssv += __shfl_xor(ssv, 2); ssv += __shfl_xor(ssv, 4);
    if ((tid & 7) == 0) rinv_v[vl] = rsqrtf(ssv);
    __syncthreads();
    const float sc = __expf(ls[0]);
    const float bias = lb[0];
    float ra0 = rinv_a[lg * 4 + 0], ra1 = rinv_a[lg * 4 + 1];
    float ra2 = rinv_a[lg * 4 + 2], ra3 = rinv_a[lg * 4 + 3];
    float accs[2][4] = {{c00,c01,c02,c03},{c10,c11,c12,c13}};
#pragma unroll
    for (int cr = 0; cr < 2; ++cr) {
        int t = rg * 2 + cr;
        float rv = rinv_v[t] * sc;
        float4 o;
        o.x = accs[cr][0] * rv * ra0 + bias;
        o.y = accs[cr][1] * rv * ra1 + bias;
        o.z = accs[cr][2] * rv * ra2 + bias;
        o.w = accs[cr][3] * rv * ra3 + bias;
        *(float4*)(out + (size_t)b * 65536 + (size_t)t * 2048 + lc * 64 + lg * 4) = o;
    }
}

// ---------------- launch ----------------
extern "C" void kernel_launch(void* const* d_in, const int* in_sizes, int n_in,
                              void* d_out, int out_size, void* d_ws, size_t ws_size,
                              hipStream_t stream) {
    (void)in_sizes; (void)n_in; (void)out_size;
    const float* video = (const float*)d_in[0];
    const float* audio = (const float*)d_in[1];
    const float* probe = (const float*)d_in[2];
    const float* wq    = (const float*)d_in[3];
    const float* wk    = (const float*)d_in[4];
    const float* wv    = (const float*)d_in[5];
    const float* bq    = (const float*)d_in[6];
    const float* bk    = (const float*)d_in[7];
    const float* bv    = (const float*)d_in[8];
    const float* wo    = (const float*)d_in[9];
    const float* bo    = (const float*)d_in[10];
    const float* lng   = (const float*)d_in[11];
    const float* lnb   = (const float*)d_in[12];
    const float* pw    = (const float*)d_in[13];
    const float* pb    = (const float*)d_in[14];
    const float* ls    = (const float*)d_in[15];
    const float* lb    = (const float*)d_in[16];
    float* ws  = (float*)d_ws;
    float* out = (float*)d_out;
    if (ws_size < FB_FLOATS * sizeof(float)) return;

    float* qwt  = ws + FB_QWT;   // [16][1024] h-major
    float* qbs  = ws + FB_QB;
    float* qf   = ws + FB_QF;
    float* ctxx = ws + FB_CTXX;  // bf16 payload
    float* ctxp = ws + FB_CTXP;
    float* poolp= ws + FB_POOLP;
    float* lno  = ws + FB_LNO;
    float* vtp  = ws + FB_VTP;

    k_qflat<<<dim3(1024), dim3(256), 0, stream>>>(probe, wq, bq, qf);
    k_qwt<<<dim3(16, 16), dim3(64), 0, stream>>>(qf, wk, bk, qwt, qbs);
    k1_attn<<<dim3(256), dim3(512), 0, stream>>>(video, qwt, qbs, ctxx);
    // G1: ctxx_bf16 (head-block diagonal) @ wv^T -> ctxp  [K=1024 split 2]
    k_gemm2<0, 1><<<dim3(16, 16, 2), dim3(256), 0, stream>>>(ctxx, nullptr, nullptr, wv, ctxp,
                                                             16384u, 1024u, 1024u);
    // G2: (ctxp0+ctxp1+bv) @ wo^T -> poolp                [K=1024 split 2]
    k_gemm2<1, 0><<<dim3(16, 16, 2), dim3(256), 0, stream>>>(ctxp, ctxp + 262144u, bv, wo, poolp,
                                                             1024u, 0u, 1024u);
    k_ln<<<dim3(256), dim3(256), 0, stream>>>(poolp, bo, lng, lnb, lno);
    // G3: lno @ pw^T -> vtp                               [K=1024 split 2]
    k_gemm2<0, 0><<<dim3(16, 8, 2), dim3(256), 0, stream>>>(lno, nullptr, nullptr, pw, vtp,
                                                            1024u, 0u, 512u);
    k_sim<<<dim3(32, 8), dim3(256), 0, stream>>>(vtp, pb, audio, ls, lb, out);
}